// Round 5
// baseline (1052.015 us; speedup 1.0000x reference)
//
#include <hip/hip_runtime.h>
#include <cstdint>
#include <cstddef>

// GraphCluster: 3-layer GCN + assign head, 100K nodes / 1.6M edges.
// R1: hierarchical scan. R2: f16-MFMA GEMMs, dinv folded into GEMM epilogue.
// R3: f16 intermediate pipeline. R4: bucketed CSR fill (kills 107MB of
// random-scatter line writebacks; LDS cursors for exact placement).

#define SCAN_CHUNK 2048

typedef _Float16 half8 __attribute__((ext_vector_type(8)));
typedef _Float16 half4 __attribute__((ext_vector_type(4)));
typedef float floatx4 __attribute__((ext_vector_type(4)));

// ---------------------------------------------------------------- CSR build
__global__ __launch_bounds__(256) void count_edges_k(const int* __restrict__ dst, int E,
                                                     int* __restrict__ cnt) {
  int idx = blockIdx.x * blockDim.x + threadIdx.x;
  int stride = gridDim.x * blockDim.x;
  for (int e = idx; e < E; e += stride) atomicAdd(&cnt[dst[e]], 1);
}

__global__ __launch_bounds__(256) void dinv_k(const int* __restrict__ cnt,
                                              float* __restrict__ dinv, int N) {
  int i = blockIdx.x * blockDim.x + threadIdx.x;
  if (i < N) dinv[i] = rsqrtf((float)(cnt[i] + 1));  // +1 self-loop
}

__global__ __launch_bounds__(256) void scan_partial_k(const int* __restrict__ cnt, int N,
                                                      int* __restrict__ bsum) {
  __shared__ int red[256];
  int b = blockIdx.x, t = threadIdx.x;
  int base = b * SCAN_CHUNK + t * 8;
  int s = 0;
#pragma unroll
  for (int i = 0; i < 8; ++i) {
    int idx = base + i;
    if (idx < N) s += cnt[idx];
  }
  red[t] = s;
  __syncthreads();
  for (int off = 128; off > 0; off >>= 1) {
    if (t < off) red[t] += red[t + off];
    __syncthreads();
  }
  if (t == 0) bsum[b] = red[0];
}

__global__ __launch_bounds__(64) void scan_bsum_k(int* __restrict__ bsum, int NB) {
  int lane = threadIdx.x;
  int per = (NB + 63) >> 6;
  int beg = lane * per;
  int end = min(beg + per, NB);
  int s = 0;
  for (int i = beg; i < end; ++i) s += bsum[i];
  int ps = s;
  for (int off = 1; off < 64; off <<= 1) {
    int u = __shfl_up(ps, off, 64);
    if (lane >= off) ps += u;
  }
  int run = ps - s;
  for (int i = beg; i < end; ++i) {
    int c = bsum[i];
    bsum[i] = run;
    run += c;
  }
}

__global__ __launch_bounds__(256) void scan_apply_k(const int* __restrict__ cnt,
                                                    const int* __restrict__ bsum_excl, int N,
                                                    int* __restrict__ rowptr,
                                                    int* __restrict__ cursor, int E) {
  __shared__ int wave_sums[4];
  int b = blockIdx.x, t = threadIdx.x;
  int base = b * SCAN_CHUNK + t * 8;
  int v[8];
  int s = 0;
#pragma unroll
  for (int i = 0; i < 8; ++i) {
    int idx = base + i;
    v[i] = (idx < N) ? cnt[idx] : 0;
    s += v[i];
  }
  int lane = t & 63, wave = t >> 6;
  int ps = s;
  for (int off = 1; off < 64; off <<= 1) {
    int u = __shfl_up(ps, off, 64);
    if (lane >= off) ps += u;
  }
  if (lane == 63) wave_sums[wave] = ps;
  __syncthreads();
  int woff = 0;
  for (int w = 0; w < 4; ++w)
    if (w < wave) woff += wave_sums[w];
  int excl = woff + (ps - s) + bsum_excl[b];
#pragma unroll
  for (int i = 0; i < 8; ++i) {
    int idx = base + i;
    if (idx < N) {
      rowptr[idx] = excl;
      cursor[idx] = excl;
      excl += v[i];
    }
  }
  if (b == 0 && t == 0) rowptr[N] = E;
}

// Fallback generic fill (N too large for packed path)
__global__ __launch_bounds__(256) void fill_k(const int* __restrict__ src,
                                              const int* __restrict__ dst, int E,
                                              int* __restrict__ cursor, int* __restrict__ col) {
  int idx = blockIdx.x * blockDim.x + threadIdx.x;
  int stride = gridDim.x * blockDim.x;
  for (int e = idx; e < E; e += stride) {
    int d = dst[e];
    int pos = atomicAdd(&cursor[d], 1);
    col[pos] = src[e];
  }
}

// --- bucketed fill (requires N <= 2^17 so (dst&127)<<17 | src fits in u32) ---
__global__ __launch_bounds__(256) void bcursor_init_k(const int* __restrict__ rowptr,
                                                      int* __restrict__ bcursor, int NBUK) {
  int b = blockIdx.x * blockDim.x + threadIdx.x;
  if (b < NBUK) bcursor[b] = rowptr[b << 7];
}

// Pass B: scatter packed edges into bucket-ordered tmp (782 sequential windows).
__global__ __launch_bounds__(256) void bucket_scatter_k(const int* __restrict__ src,
                                                        const int* __restrict__ dst, int E,
                                                        int* __restrict__ bcursor,
                                                        uint32_t* __restrict__ tmp) {
  int idx = blockIdx.x * blockDim.x + threadIdx.x;
  int stride = gridDim.x * blockDim.x;
  for (int e = idx; e < E; e += stride) {
    int d = dst[e];
    int b = d >> 7;
    int pos = atomicAdd(&bcursor[b], 1);
    tmp[pos] = ((uint32_t)(d & 127) << 17) | (uint32_t)src[e];
  }
}

// Pass C: one block per bucket; LDS cursors -> exact col positions (8KB window).
__global__ __launch_bounds__(256) void fill_bucket_k(const uint32_t* __restrict__ tmp,
                                                     const int* __restrict__ rowptr, int N,
                                                     int* __restrict__ col) {
  __shared__ int cur[128];
  int b = blockIdx.x;
  int n0 = b << 7;
  int t = threadIdx.x;
  if (t < 128 && n0 + t < N) cur[t] = rowptr[n0 + t];
  __syncthreads();
  int sbeg = rowptr[n0];
  int send = rowptr[min(n0 + 128, N)];
  for (int e = sbeg + t; e < send; e += 256) {
    uint32_t v = tmp[e];
    int pos = atomicAdd(&cur[v >> 17], 1);
    col[pos] = (int)(v & 0x1FFFF);
  }
}

// ---------------------------------------------------------------- f16 MFMA GEMM
template <bool SIG, bool HIN, bool HOUT, int NT>
__global__ __launch_bounds__(256) void gemm_mfma_k(const void* __restrict__ Av,
                                                   const float* __restrict__ W,
                                                   const float* __restrict__ bias,
                                                   const float* __restrict__ scale,
                                                   void* __restrict__ outv, int N) {
  constexpr int NCOL = NT * 16;
  __shared__ __align__(16) _Float16 Af[64][136];
  __shared__ __align__(16) _Float16 Wf[NCOL][136];
  const int tid = threadIdx.x;
  const int r0 = blockIdx.x * 64;
  if (HIN) {
    const _Float16* A = (const _Float16*)Av;
    for (int idx = tid; idx < 64 * 16; idx += 256) {
      int row = idx >> 4;
      int c8 = (idx & 15) << 3;
      half8 v = {0, 0, 0, 0, 0, 0, 0, 0};
      int gr = r0 + row;
      if (gr < N) v = *(const half8*)(A + (size_t)gr * 128 + c8);
      *(half8*)&Af[row][c8] = v;
    }
  } else {
    const float* A = (const float*)Av;
    for (int idx = tid; idx < 64 * 32; idx += 256) {
      int row = idx >> 5;
      int c4 = (idx & 31) << 2;
      float4 v = make_float4(0.f, 0.f, 0.f, 0.f);
      int gr = r0 + row;
      if (gr < N) v = *(const float4*)(A + (size_t)gr * 128 + c4);
      Af[row][c4 + 0] = (_Float16)v.x;
      Af[row][c4 + 1] = (_Float16)v.y;
      Af[row][c4 + 2] = (_Float16)v.z;
      Af[row][c4 + 3] = (_Float16)v.w;
    }
  }
  for (int idx = tid; idx < 128 * (NCOL / 4); idx += 256) {
    int k = idx / (NCOL / 4);
    int n4 = (idx % (NCOL / 4)) << 2;
    float4 v = *(const float4*)(W + (size_t)k * NCOL + n4);
    Wf[n4 + 0][k] = (_Float16)v.x;
    Wf[n4 + 1][k] = (_Float16)v.y;
    Wf[n4 + 2][k] = (_Float16)v.z;
    Wf[n4 + 3][k] = (_Float16)v.w;
  }
  __syncthreads();
  const int w = tid >> 6, lane = tid & 63;
  const int m = lane & 15, q = lane >> 4;
  floatx4 acc[NT];
#pragma unroll
  for (int t = 0; t < NT; ++t) acc[t] = (floatx4){0.f, 0.f, 0.f, 0.f};
#pragma unroll
  for (int kt = 0; kt < 128; kt += 32) {
    half8 a = *(const half8*)&Af[w * 16 + m][kt + q * 8];
#pragma unroll
    for (int t = 0; t < NT; ++t) {
      half8 b = *(const half8*)&Wf[t * 16 + m][kt + q * 8];
      acc[t] = __builtin_amdgcn_mfma_f32_16x16x32_f16(a, b, acc[t], 0, 0, 0);
    }
  }
#pragma unroll
  for (int r = 0; r < 4; ++r) {
    int row = r0 + w * 16 + q * 4 + r;
    if (row >= N) continue;
    float sc = scale ? scale[row] : 1.f;
#pragma unroll
    for (int t = 0; t < NT; ++t) {
      int colg = t * 16 + m;
      float v = acc[t][r];
      if (bias) v += bias[colg];
      if (SIG) v = 1.f / (1.f + __expf(-v));
      v *= sc;
      if (HOUT)
        ((_Float16*)outv)[(size_t)row * NCOL + colg] = (_Float16)v;
      else
        ((float*)outv)[(size_t)row * NCOL + colg] = v;
    }
  }
}

// ---------------------------------------------------------------- aggregation
__global__ __launch_bounds__(256) void agg128h_k(const _Float16* __restrict__ xw,
                                                 const int* __restrict__ rowptr,
                                                 const int* __restrict__ col,
                                                 const float* __restrict__ dinv,
                                                 const float* __restrict__ bias,
                                                 _Float16* __restrict__ out, int N) {
  int node = blockIdx.x * 4 + (threadIdx.x >> 6);
  if (node >= N) return;
  int lane = threadIdx.x & 63;
  int fl = lane & 31;
  int j = lane >> 5;
  int beg = rowptr[node];
  int end = rowptr[node + 1];
  const _Float16* base = xw + (size_t)fl * 4;
  float a0 = 0.f, a1 = 0.f, a2 = 0.f, a3 = 0.f;
  int e = beg + j;
  for (; e + 6 < end; e += 8) {
    int s0 = col[e], s1 = col[e + 2], s2 = col[e + 4], s3 = col[e + 6];
    half4 v0 = *(const half4*)(base + (size_t)s0 * 128);
    half4 v1 = *(const half4*)(base + (size_t)s1 * 128);
    half4 v2 = *(const half4*)(base + (size_t)s2 * 128);
    half4 v3 = *(const half4*)(base + (size_t)s3 * 128);
    a0 += ((float)v0[0] + (float)v1[0]) + ((float)v2[0] + (float)v3[0]);
    a1 += ((float)v0[1] + (float)v1[1]) + ((float)v2[1] + (float)v3[1]);
    a2 += ((float)v0[2] + (float)v1[2]) + ((float)v2[2] + (float)v3[2]);
    a3 += ((float)v0[3] + (float)v1[3]) + ((float)v2[3] + (float)v3[3]);
  }
  for (; e < end; e += 2) {
    half4 v = *(const half4*)(base + (size_t)col[e] * 128);
    a0 += (float)v[0];
    a1 += (float)v[1];
    a2 += (float)v[2];
    a3 += (float)v[3];
  }
  if (j == 0) {
    half4 v = *(const half4*)(base + (size_t)node * 128);
    a0 += (float)v[0];
    a1 += (float)v[1];
    a2 += (float)v[2];
    a3 += (float)v[3];
  }
  a0 += __shfl_xor(a0, 32, 64);
  a1 += __shfl_xor(a1, 32, 64);
  a2 += __shfl_xor(a2, 32, 64);
  a3 += __shfl_xor(a3, 32, 64);
  if (j == 0) {
    float di = dinv[node];
    float4 bb = *(const float4*)(bias + fl * 4);
    half4 o;
    o[0] = (_Float16)fmaf(a0, di, bb.x);
    o[1] = (_Float16)fmaf(a1, di, bb.y);
    o[2] = (_Float16)fmaf(a2, di, bb.z);
    o[3] = (_Float16)fmaf(a3, di, bb.w);
    *(half4*)(out + (size_t)node * 128 + fl * 4) = o;
  }
}

__global__ __launch_bounds__(256) void agg16_k(const float* __restrict__ xw,
                                               const int* __restrict__ rowptr,
                                               const int* __restrict__ col,
                                               const float* __restrict__ dinv,
                                               const float* __restrict__ bias,
                                               float* __restrict__ out, int N) {
  int node = blockIdx.x * 4 + (threadIdx.x >> 6);
  if (node >= N) return;
  int lane = threadIdx.x & 63;
  int f = lane & 15;
  int j = lane >> 4;
  int beg = rowptr[node];
  int end = rowptr[node + 1];
  float acc = 0.f;
  for (int e = beg + j; e < end; e += 4) {
    acc += xw[(size_t)col[e] * 16 + f];
  }
  acc += __shfl_xor(acc, 16, 64);
  acc += __shfl_xor(acc, 32, 64);
  float o = fmaf(acc + xw[(size_t)node * 16 + f], dinv[node], bias[f]);
  if (j == 0) out[(size_t)node * 16 + f] = o;
}

// ---------------------------------------------------------------- launch
extern "C" void kernel_launch(void* const* d_in, const int* in_sizes, int n_in,
                              void* d_out, int out_size, void* d_ws, size_t ws_size,
                              hipStream_t stream) {
  const int* adj = (const int*)d_in[0];
  const float* X = (const float*)d_in[1];
  const float* fc1_W = (const float*)d_in[2];
  const float* fc1_b = (const float*)d_in[3];
  const float* fc2_W = (const float*)d_in[4];
  const float* fc2_b = (const float*)d_in[5];
  const float* gcn_W = (const float*)d_in[6];
  const float* gcn_b = (const float*)d_in[7];
  const float* assign_W = (const float*)d_in[8];
  const float* assign_b = (const float*)d_in[9];
  const int E = in_sizes[0] / 2;
  const int N = in_sizes[1] / 128;
  const int* src = adj;
  const int* dst = adj + E;

  char* ws = (char*)d_ws;
  size_t off = 0;
  auto alloc = [&](size_t bytes) {
    void* p = ws + off;
    off = (off + bytes + 511) & ~(size_t)511;
    return p;
  };
  _Float16* Ph = (_Float16*)alloc((size_t)N * 128 * 2);  // 25.6 MB
  _Float16* Qh = (_Float16*)alloc((size_t)N * 128 * 2);  // 25.6 MB
  int* cnt = (int*)alloc((size_t)N * 4);
  float* dinv = (float*)alloc((size_t)N * 4);
  int* rowptr = (int*)alloc((size_t)(N + 1) * 4);
  int* cursor = (int*)alloc((size_t)N * 4);
  int* col = (int*)alloc((size_t)E * 4);
  uint32_t* tmp = (uint32_t*)alloc((size_t)E * 4);
  int* bsum = (int*)alloc(4096);
  int* bcursor = (int*)alloc(((size_t)(N + 127) / 128) * 4 + 512);
  float* S = (float*)Ph;  // assign xw [N,16] fp32 reuses Ph

  const int NB = (N + SCAN_CHUNK - 1) / SCAN_CHUNK;
  const int NBUK = (N + 127) >> 7;

  hipMemsetAsync(cnt, 0, (size_t)N * 4, stream);
  count_edges_k<<<2048, 256, 0, stream>>>(dst, E, cnt);
  dinv_k<<<(N + 255) / 256, 256, 0, stream>>>(cnt, dinv, N);
  scan_partial_k<<<NB, 256, 0, stream>>>(cnt, N, bsum);
  scan_bsum_k<<<1, 64, 0, stream>>>(bsum, NB);
  scan_apply_k<<<NB, 256, 0, stream>>>(cnt, bsum, N, rowptr, cursor, E);
  if (N <= (1 << 17)) {
    bcursor_init_k<<<(NBUK + 255) / 256, 256, 0, stream>>>(rowptr, bcursor, NBUK);
    bucket_scatter_k<<<2048, 256, 0, stream>>>(src, dst, E, bcursor, tmp);
    fill_bucket_k<<<NBUK, 256, 0, stream>>>(tmp, rowptr, N, col);
  } else {
    fill_k<<<2048, 256, 0, stream>>>(src, dst, E, cursor, col);
  }

  int gb = (N + 63) / 64;
  int ab = (N + 3) / 4;
  gemm_mfma_k<true, false, true, 8><<<gb, 256, 0, stream>>>(X, fc1_W, fc1_b, nullptr, Ph, N);
  gemm_mfma_k<true, true, true, 8><<<gb, 256, 0, stream>>>(Ph, fc2_W, fc2_b, nullptr, Qh, N);
  for (int l = 0; l < 3; ++l) {
    gemm_mfma_k<false, true, true, 8><<<gb, 256, 0, stream>>>(
        Qh, gcn_W + (size_t)l * 128 * 128, nullptr, dinv, Ph, N);
    agg128h_k<<<ab, 256, 0, stream>>>(Ph, rowptr, col, dinv, gcn_b + (size_t)l * 128, Qh, N);
  }
  gemm_mfma_k<false, true, false, 1><<<gb, 256, 0, stream>>>(Qh, assign_W, nullptr, dinv, S, N);
  agg16_k<<<ab, 256, 0, stream>>>(S, rowptr, col, dinv, assign_b, (float*)d_out, N);
}

// Round 6
// 767.688 us; speedup vs baseline: 1.3704x; 1.3704x over previous
//
#include <hip/hip_runtime.h>
#include <cstdint>
#include <cstddef>

// GraphCluster: 3-layer GCN + assign head, 100K nodes / 1.6M edges.
// R1: hierarchical scan. R2: f16-MFMA GEMMs, dinv folded into epilogue.
// R3: f16 intermediate pipeline. R4 bucketed fill REVERTED in R5 (782 hot
// cursors serialized: 378us vs 120us; many cold atomics >> few hot ones).
// R5: fill_k + nontemporal col stores; agg 4-edge x half8 gathers (16B/lane).

#define SCAN_CHUNK 2048

typedef _Float16 half8 __attribute__((ext_vector_type(8)));
typedef _Float16 half4 __attribute__((ext_vector_type(4)));
typedef float floatx4 __attribute__((ext_vector_type(4)));

// ---------------------------------------------------------------- CSR build
__global__ __launch_bounds__(256) void count_edges_k(const int* __restrict__ dst, int E,
                                                     int* __restrict__ cnt) {
  int idx = blockIdx.x * blockDim.x + threadIdx.x;
  int stride = gridDim.x * blockDim.x;
  for (int e = idx; e < E; e += stride) atomicAdd(&cnt[dst[e]], 1);
}

__global__ __launch_bounds__(256) void dinv_k(const int* __restrict__ cnt,
                                              float* __restrict__ dinv, int N) {
  int i = blockIdx.x * blockDim.x + threadIdx.x;
  if (i < N) dinv[i] = rsqrtf((float)(cnt[i] + 1));  // +1 self-loop
}

__global__ __launch_bounds__(256) void scan_partial_k(const int* __restrict__ cnt, int N,
                                                      int* __restrict__ bsum) {
  __shared__ int red[256];
  int b = blockIdx.x, t = threadIdx.x;
  int base = b * SCAN_CHUNK + t * 8;
  int s = 0;
#pragma unroll
  for (int i = 0; i < 8; ++i) {
    int idx = base + i;
    if (idx < N) s += cnt[idx];
  }
  red[t] = s;
  __syncthreads();
  for (int off = 128; off > 0; off >>= 1) {
    if (t < off) red[t] += red[t + off];
    __syncthreads();
  }
  if (t == 0) bsum[b] = red[0];
}

__global__ __launch_bounds__(64) void scan_bsum_k(int* __restrict__ bsum, int NB) {
  int lane = threadIdx.x;
  int per = (NB + 63) >> 6;
  int beg = lane * per;
  int end = min(beg + per, NB);
  int s = 0;
  for (int i = beg; i < end; ++i) s += bsum[i];
  int ps = s;
  for (int off = 1; off < 64; off <<= 1) {
    int u = __shfl_up(ps, off, 64);
    if (lane >= off) ps += u;
  }
  int run = ps - s;
  for (int i = beg; i < end; ++i) {
    int c = bsum[i];
    bsum[i] = run;
    run += c;
  }
}

__global__ __launch_bounds__(256) void scan_apply_k(const int* __restrict__ cnt,
                                                    const int* __restrict__ bsum_excl, int N,
                                                    int* __restrict__ rowptr,
                                                    int* __restrict__ cursor, int E) {
  __shared__ int wave_sums[4];
  int b = blockIdx.x, t = threadIdx.x;
  int base = b * SCAN_CHUNK + t * 8;
  int v[8];
  int s = 0;
#pragma unroll
  for (int i = 0; i < 8; ++i) {
    int idx = base + i;
    v[i] = (idx < N) ? cnt[idx] : 0;
    s += v[i];
  }
  int lane = t & 63, wave = t >> 6;
  int ps = s;
  for (int off = 1; off < 64; off <<= 1) {
    int u = __shfl_up(ps, off, 64);
    if (lane >= off) ps += u;
  }
  if (lane == 63) wave_sums[wave] = ps;
  __syncthreads();
  int woff = 0;
  for (int w = 0; w < 4; ++w)
    if (w < wave) woff += wave_sums[w];
  int excl = woff + (ps - s) + bsum_excl[b];
#pragma unroll
  for (int i = 0; i < 8; ++i) {
    int idx = base + i;
    if (idx < N) {
      rowptr[idx] = excl;
      cursor[idx] = excl;
      excl += v[i];
    }
  }
  if (b == 0 && t == 0) rowptr[N] = E;
}

__global__ __launch_bounds__(256) void fill_k(const int* __restrict__ src,
                                              const int* __restrict__ dst, int E,
                                              int* __restrict__ cursor, int* __restrict__ col) {
  int idx = blockIdx.x * blockDim.x + threadIdx.x;
  int stride = gridDim.x * blockDim.x;
  for (int e = idx; e < E; e += stride) {
    int d = dst[e];
    int pos = atomicAdd(&cursor[d], 1);
    __builtin_nontemporal_store(src[e], &col[pos]);
  }
}

// ---------------------------------------------------------------- f16 MFMA GEMM
template <bool SIG, bool HIN, bool HOUT, int NT>
__global__ __launch_bounds__(256) void gemm_mfma_k(const void* __restrict__ Av,
                                                   const float* __restrict__ W,
                                                   const float* __restrict__ bias,
                                                   const float* __restrict__ scale,
                                                   void* __restrict__ outv, int N) {
  constexpr int NCOL = NT * 16;
  __shared__ __align__(16) _Float16 Af[64][136];
  __shared__ __align__(16) _Float16 Wf[NCOL][136];
  const int tid = threadIdx.x;
  const int r0 = blockIdx.x * 64;
  if (HIN) {
    const _Float16* A = (const _Float16*)Av;
    for (int idx = tid; idx < 64 * 16; idx += 256) {
      int row = idx >> 4;
      int c8 = (idx & 15) << 3;
      half8 v = {0, 0, 0, 0, 0, 0, 0, 0};
      int gr = r0 + row;
      if (gr < N) v = *(const half8*)(A + (size_t)gr * 128 + c8);
      *(half8*)&Af[row][c8] = v;
    }
  } else {
    const float* A = (const float*)Av;
    for (int idx = tid; idx < 64 * 32; idx += 256) {
      int row = idx >> 5;
      int c4 = (idx & 31) << 2;
      float4 v = make_float4(0.f, 0.f, 0.f, 0.f);
      int gr = r0 + row;
      if (gr < N) v = *(const float4*)(A + (size_t)gr * 128 + c4);
      Af[row][c4 + 0] = (_Float16)v.x;
      Af[row][c4 + 1] = (_Float16)v.y;
      Af[row][c4 + 2] = (_Float16)v.z;
      Af[row][c4 + 3] = (_Float16)v.w;
    }
  }
  for (int idx = tid; idx < 128 * (NCOL / 4); idx += 256) {
    int k = idx / (NCOL / 4);
    int n4 = (idx % (NCOL / 4)) << 2;
    float4 v = *(const float4*)(W + (size_t)k * NCOL + n4);
    Wf[n4 + 0][k] = (_Float16)v.x;
    Wf[n4 + 1][k] = (_Float16)v.y;
    Wf[n4 + 2][k] = (_Float16)v.z;
    Wf[n4 + 3][k] = (_Float16)v.w;
  }
  __syncthreads();
  const int w = tid >> 6, lane = tid & 63;
  const int m = lane & 15, q = lane >> 4;
  floatx4 acc[NT];
#pragma unroll
  for (int t = 0; t < NT; ++t) acc[t] = (floatx4){0.f, 0.f, 0.f, 0.f};
#pragma unroll
  for (int kt = 0; kt < 128; kt += 32) {
    half8 a = *(const half8*)&Af[w * 16 + m][kt + q * 8];
#pragma unroll
    for (int t = 0; t < NT; ++t) {
      half8 b = *(const half8*)&Wf[t * 16 + m][kt + q * 8];
      acc[t] = __builtin_amdgcn_mfma_f32_16x16x32_f16(a, b, acc[t], 0, 0, 0);
    }
  }
#pragma unroll
  for (int r = 0; r < 4; ++r) {
    int row = r0 + w * 16 + q * 4 + r;
    if (row >= N) continue;
    float sc = scale ? scale[row] : 1.f;
#pragma unroll
    for (int t = 0; t < NT; ++t) {
      int colg = t * 16 + m;
      float v = acc[t][r];
      if (bias) v += bias[colg];
      if (SIG) v = 1.f / (1.f + __expf(-v));
      v *= sc;
      if (HOUT)
        ((_Float16*)outv)[(size_t)row * NCOL + colg] = (_Float16)v;
      else
        ((float*)outv)[(size_t)row * NCOL + colg] = v;
    }
  }
}

// ---------------------------------------------------------------- aggregation
// xw (f16, pre-scaled by dinv[row]): out[i] = b + dinv[i]*(xw[i]+sum xw[src]).
// One wave/node; 16 lanes x half8 (16B) cover the 128-f16 row; 4 edge slots
// (j=lane>>4), unrolled 4x -> 16 x 16B gathers outstanding per wave.
__global__ __launch_bounds__(256) void agg128h_k(const _Float16* __restrict__ xw,
                                                 const int* __restrict__ rowptr,
                                                 const int* __restrict__ col,
                                                 const float* __restrict__ dinv,
                                                 const float* __restrict__ bias,
                                                 _Float16* __restrict__ out, int N) {
  int node = blockIdx.x * 4 + (threadIdx.x >> 6);
  if (node >= N) return;
  int lane = threadIdx.x & 63;
  int fl = lane & 15;  // feature chunk (8 f16 = 16B)
  int j = lane >> 4;   // edge slot 0..3
  int beg = rowptr[node];
  int end = rowptr[node + 1];
  const _Float16* base = xw + (size_t)fl * 8;
  float a[8] = {0.f, 0.f, 0.f, 0.f, 0.f, 0.f, 0.f, 0.f};
  int e = beg + j;
  for (; e + 12 < end; e += 16) {
    int s0 = col[e], s1 = col[e + 4], s2 = col[e + 8], s3 = col[e + 12];
    half8 v0 = *(const half8*)(base + (size_t)s0 * 128);
    half8 v1 = *(const half8*)(base + (size_t)s1 * 128);
    half8 v2 = *(const half8*)(base + (size_t)s2 * 128);
    half8 v3 = *(const half8*)(base + (size_t)s3 * 128);
#pragma unroll
    for (int f = 0; f < 8; ++f)
      a[f] += ((float)v0[f] + (float)v1[f]) + ((float)v2[f] + (float)v3[f]);
  }
  for (; e < end; e += 4) {
    half8 v = *(const half8*)(base + (size_t)col[e] * 128);
#pragma unroll
    for (int f = 0; f < 8; ++f) a[f] += (float)v[f];
  }
  if (j == 0) {  // self-loop term once
    half8 v = *(const half8*)(base + (size_t)node * 128);
#pragma unroll
    for (int f = 0; f < 8; ++f) a[f] += (float)v[f];
  }
#pragma unroll
  for (int f = 0; f < 8; ++f) {
    a[f] += __shfl_xor(a[f], 16, 64);
    a[f] += __shfl_xor(a[f], 32, 64);
  }
  if (j == 0) {
    float di = dinv[node];
    float4 b0 = *(const float4*)(bias + fl * 8);
    float4 b1 = *(const float4*)(bias + fl * 8 + 4);
    half8 o;
    o[0] = (_Float16)fmaf(a[0], di, b0.x);
    o[1] = (_Float16)fmaf(a[1], di, b0.y);
    o[2] = (_Float16)fmaf(a[2], di, b0.z);
    o[3] = (_Float16)fmaf(a[3], di, b0.w);
    o[4] = (_Float16)fmaf(a[4], di, b1.x);
    o[5] = (_Float16)fmaf(a[5], di, b1.y);
    o[6] = (_Float16)fmaf(a[6], di, b1.z);
    o[7] = (_Float16)fmaf(a[7], di, b1.w);
    *(half8*)(out + (size_t)node * 128 + fl * 8) = o;
  }
}

__global__ __launch_bounds__(256) void agg16_k(const float* __restrict__ xw,
                                               const int* __restrict__ rowptr,
                                               const int* __restrict__ col,
                                               const float* __restrict__ dinv,
                                               const float* __restrict__ bias,
                                               float* __restrict__ out, int N) {
  int node = blockIdx.x * 4 + (threadIdx.x >> 6);
  if (node >= N) return;
  int lane = threadIdx.x & 63;
  int f = lane & 15;
  int j = lane >> 4;
  int beg = rowptr[node];
  int end = rowptr[node + 1];
  float acc = 0.f;
  for (int e = beg + j; e < end; e += 4) {
    acc += xw[(size_t)col[e] * 16 + f];
  }
  acc += __shfl_xor(acc, 16, 64);
  acc += __shfl_xor(acc, 32, 64);
  float o = fmaf(acc + xw[(size_t)node * 16 + f], dinv[node], bias[f]);
  if (j == 0) out[(size_t)node * 16 + f] = o;
}

// ---------------------------------------------------------------- launch
extern "C" void kernel_launch(void* const* d_in, const int* in_sizes, int n_in,
                              void* d_out, int out_size, void* d_ws, size_t ws_size,
                              hipStream_t stream) {
  const int* adj = (const int*)d_in[0];
  const float* X = (const float*)d_in[1];
  const float* fc1_W = (const float*)d_in[2];
  const float* fc1_b = (const float*)d_in[3];
  const float* fc2_W = (const float*)d_in[4];
  const float* fc2_b = (const float*)d_in[5];
  const float* gcn_W = (const float*)d_in[6];
  const float* gcn_b = (const float*)d_in[7];
  const float* assign_W = (const float*)d_in[8];
  const float* assign_b = (const float*)d_in[9];
  const int E = in_sizes[0] / 2;
  const int N = in_sizes[1] / 128;
  const int* src = adj;
  const int* dst = adj + E;

  char* ws = (char*)d_ws;
  size_t off = 0;
  auto alloc = [&](size_t bytes) {
    void* p = ws + off;
    off = (off + bytes + 511) & ~(size_t)511;
    return p;
  };
  _Float16* Ph = (_Float16*)alloc((size_t)N * 128 * 2);  // 25.6 MB
  _Float16* Qh = (_Float16*)alloc((size_t)N * 128 * 2);  // 25.6 MB
  int* cnt = (int*)alloc((size_t)N * 4);
  float* dinv = (float*)alloc((size_t)N * 4);
  int* rowptr = (int*)alloc((size_t)(N + 1) * 4);
  int* cursor = (int*)alloc((size_t)N * 4);
  int* col = (int*)alloc((size_t)E * 4);
  int* bsum = (int*)alloc(4096);
  float* S = (float*)Ph;  // assign xw [N,16] fp32 reuses Ph

  const int NB = (N + SCAN_CHUNK - 1) / SCAN_CHUNK;

  hipMemsetAsync(cnt, 0, (size_t)N * 4, stream);
  count_edges_k<<<2048, 256, 0, stream>>>(dst, E, cnt);
  dinv_k<<<(N + 255) / 256, 256, 0, stream>>>(cnt, dinv, N);
  scan_partial_k<<<NB, 256, 0, stream>>>(cnt, N, bsum);
  scan_bsum_k<<<1, 64, 0, stream>>>(bsum, NB);
  scan_apply_k<<<NB, 256, 0, stream>>>(cnt, bsum, N, rowptr, cursor, E);
  fill_k<<<2048, 256, 0, stream>>>(src, dst, E, cursor, col);

  int gb = (N + 63) / 64;
  int ab = (N + 3) / 4;
  gemm_mfma_k<true, false, true, 8><<<gb, 256, 0, stream>>>(X, fc1_W, fc1_b, nullptr, Ph, N);
  gemm_mfma_k<true, true, true, 8><<<gb, 256, 0, stream>>>(Ph, fc2_W, fc2_b, nullptr, Qh, N);
  for (int l = 0; l < 3; ++l) {
    gemm_mfma_k<false, true, true, 8><<<gb, 256, 0, stream>>>(
        Qh, gcn_W + (size_t)l * 128 * 128, nullptr, dinv, Ph, N);
    agg128h_k<<<ab, 256, 0, stream>>>(Ph, rowptr, col, dinv, gcn_b + (size_t)l * 128, Qh, N);
  }
  gemm_mfma_k<false, true, false, 1><<<gb, 256, 0, stream>>>(Qh, assign_W, nullptr, dinv, S, N);
  agg16_k<<<ab, 256, 0, stream>>>(S, rowptr, col, dinv, assign_b, (float*)d_out, N);
}